// Round 4
// baseline (312.511 us; speedup 1.0000x reference)
//
#include <hip/hip_runtime.h>
#include <hip/hip_bf16.h>

typedef short s16x8 __attribute__((ext_vector_type(8)));
typedef float f32x4 __attribute__((ext_vector_type(4)));
typedef float f32x16 __attribute__((ext_vector_type(16)));
typedef unsigned short u16;
typedef unsigned int   u32;
typedef u16 u16x4 __attribute__((ext_vector_type(4)));

#define SEQ  1370
#define CH   1024
#define NH   16
#define HD   64
#define BN   5480      // 4*1370
#define MPAD 5504      // 43*128
#define NPAD 1408      // 22*64
#define NQT  43        // ceil(1370/32)
#define NKT64 22       // NPAD/64

// log2(e) folded into q scale: exp(x) = exp2(x*log2e)
#define QSCALE 0.18033688f   // 0.125 * 1.44269504089

__device__ __forceinline__ u16 f2bf(float f){
  union { float f; unsigned u; } v; v.f = f;
  unsigned u = v.u;
  return (u16)((u + 0x7FFFu + ((u >> 16) & 1u)) >> 16);   // RNE
}

__device__ __forceinline__ u32 cvt_pk_bf16(float lo, float hi){
  u32 r;
  asm("v_cvt_pk_bf16_f32 %0, %1, %2" : "=v"(r) : "v"(lo), "v"(hi));
  return r;
}

#define GLOAD16(gp, lp) __builtin_amdgcn_global_load_lds( \
    (const __attribute__((address_space(1))) void*)(gp), \
    (__attribute__((address_space(3))) void*)(lp), 16, 0, 0)

// ---- casts ----
__global__ __launch_bounds__(256) void k_cast_tokens(const float* __restrict__ in, u16* __restrict__ out){
  int i = blockIdx.x * 256 + threadIdx.x;
  if(i >= MPAD*CH) return;
  int row = i >> 10;
  out[i] = (row < BN) ? f2bf(in[i]) : (u16)0;   // zero-pad M tail
}

__global__ __launch_bounds__(256) void k_cast(const float* __restrict__ in, u16* __restrict__ out, int n){
  int i = blockIdx.x * 256 + threadIdx.x;
  if(i < n) out[i] = f2bf(in[i]);
}

// ---- m97-structure NT GEMM: 128xNT tile, BK=32, global_load_lds, 4 waves ----
// C[m][n] = sum_k A[m][k]*B[n][k] + bias[n]
// MODE 0 (NT=128): QKV epilogue; grid 1056 (8 XCD x 132), region 11x x 12y
// MODE 1 (NT=64):  proj epilogue; grid 704  (8 XCD x 88),  region 11x x 8y
template<int MODE, int NT>
__global__ __launch_bounds__(256,2) void k_gemm128(
    const u16* __restrict__ A, const u16* __restrict__ Bw, const float* __restrict__ bias,
    u16* __restrict__ q, u16* __restrict__ kk, u16* __restrict__ vv, float* __restrict__ out)
{
  constexpr int NF = NT/32;      // N frags per wave: NT=128 -> 4, NT=64 -> 2
  __shared__ u16 As[128*32];     // linear — global_load_lds needs linear dest
  __shared__ u16 Bs[NT*32];
  const int t = threadIdx.x;
  const int lane = t & 63;
  const int w = t >> 6;
  const int wm = w >> 1, wn = w & 1;
  const int g = lane >> 4, lr = lane & 15;

  // XCD-aware 2D region decomposition (each XCD: 11 x-panels, YLOC y-panels)
  const int bid = blockIdx.x;
  const int xcd = bid & 7, idx = bid >> 3;
  const int xr = xcd & 3, yr = xcd >> 2;
  constexpr int YLOC = (MODE == 0) ? 12 : 8;
  const int x = xr*11 + idx % 11;
  const int y = yr*YLOC + idx / 11;
  if(x >= MPAD/128) return;
  const int m0 = x*128, n0 = y*NT;

  const u16* ga0 = A  + (size_t)(m0 + (t >> 2)) * 1024 + (t & 3) * 8;
  const u16* gb0 = Bw + (size_t)(n0 + (t >> 2)) * 1024 + (t & 3) * 8;
  u16* law = As + w * 512;
  u16* lbw = Bs + w * 512;

  f32x4 z = {0.f,0.f,0.f,0.f};
  f32x4 acc[4][NF];
#pragma unroll
  for(int mf=0;mf<4;mf++)
#pragma unroll
    for(int nf=0;nf<NF;nf++) acc[mf][nf] = z;

  for(int k0 = 0; k0 < 1024; k0 += 32){
    GLOAD16(ga0 + k0,             law);
    GLOAD16(ga0 + k0 + 64*1024,   law + 2048);
    GLOAD16(gb0 + k0,             lbw);
    if constexpr (NT == 128) GLOAD16(gb0 + k0 + 64*1024, lbw + 2048);
    __syncthreads();              // vmcnt(0) drain + barrier: tiles resident
    s16x8 af[4], bf[NF];
#pragma unroll
    for(int mf = 0; mf < 4; mf++)
      af[mf] = *reinterpret_cast<const s16x8*>(&As[(wm*64 + mf*16 + lr)*32 + g*8]);
#pragma unroll
    for(int nf = 0; nf < NF; nf++)
      bf[nf] = *reinterpret_cast<const s16x8*>(&Bs[(wn*16*NF + nf*16 + lr)*32 + g*8]);
#pragma unroll
    for(int mf = 0; mf < 4; mf++)
#pragma unroll
      for(int nf = 0; nf < NF; nf++)
        acc[mf][nf] = __builtin_amdgcn_mfma_f32_16x16x32_bf16(af[mf], bf[nf], acc[mf][nf], 0,0,0);
    __syncthreads();              // all reads done before next overwrite
  }

#pragma unroll
  for(int mf = 0; mf < 4; mf++){
#pragma unroll
    for(int nf = 0; nf < NF; nf++){
      int colc = n0 + wn*16*NF + nf*16 + lr;
      float bb = bias[colc];
#pragma unroll
      for(int r = 0; r < 4; r++){
        int row = m0 + wm*64 + mf*16 + g*4 + r;   // C/D: col=lane&15, row=(lane>>4)*4+reg
        if(row >= BN) continue;
        float v = acc[mf][nf][r] + bb;
        if constexpr (MODE == 0){
          int b = row / SEQ, n = row - b*SEQ;
          int tt = colc >> 10, h = (colc >> 6) & 15, cc = colc & 63;
          size_t bh = (size_t)(b*NH + h);
          if(tt == 0)      q [(bh*NPAD + n)*HD + cc] = f2bf(v * QSCALE);
          else if(tt == 1) kk[(bh*NPAD + n)*HD + cc] = f2bf(v);
          else             vv[(bh*NPAD + n)*HD + cc] = f2bf(v);
        } else {
          out[(size_t)row * CH + colc] = v;
        }
      }
    }
  }
}

// ---- V[bh][n][cc] -> Vt[bh][cc][n], zero-fills n in [SEQ,NPAD) ----
__global__ __launch_bounds__(256) void k_transpose_v(const u16* __restrict__ V, u16* __restrict__ Vt){
  __shared__ u16 Ts[64][80];
  const int bh = blockIdx.x, nt = blockIdx.y;
  const int n0 = nt * 64;
  const int t = threadIdx.x;
  const int row = t >> 3;
  const int c8  = (t & 7) * 8;
  const u16* vb = V + (size_t)bh * NPAD * HD;
  for(int i = 0; i < 2; i++){
    int r = row + i*32;
    int n = n0 + r;
    s16x8 val = {0,0,0,0,0,0,0,0};
    if(n < SEQ) val = *reinterpret_cast<const s16x8*>(vb + (size_t)n*HD + c8);
    *reinterpret_cast<s16x8*>(&Ts[r][c8]) = val;
  }
  __syncthreads();
  u16* vtb = Vt + (size_t)bh * HD * NPAD;
  for(int i = 0; i < 2; i++){
    int cc = row + i*32;
    s16x8 o;
    for(int j = 0; j < 8; j++) o[j] = Ts[c8 + j][cc];
    *reinterpret_cast<s16x8*>(vtb + (size_t)cc*NPAD + n0 + c8) = o;
  }
}

// ---- flash attention v4: 4 waves/block share bh (K/V L1-shared, lockstep via raw
// s_barrier — NOT __syncthreads, which drains vmcnt and kills the prefetch),
// XCD swizzle keeps each bh's K/V in one XCD's L2. ----
__global__ __launch_bounds__(256,3) void k_attn4(
    const u16* __restrict__ Q, const u16* __restrict__ K,
    const u16* __restrict__ Vt, u16* __restrict__ O)
{
  const int bid = blockIdx.x;                 // 0..703
  const int swz = (bid & 7)*88 + (bid >> 3);  // bijective: 704 = 8*88
  const int bh = swz / 11;                    // 8 bh per XCD -> K/V 2.9MB in L2
  const int qg = swz - bh*11;
  const int w = threadIdx.x >> 6;
  int qt = qg*4 + w;
  const bool wr = (qt < NQT);
  if(!wr) qt = NQT - 1;                       // dup wave: recompute, no store
  const int lane = threadIdx.x & 63;
  const int col = lane & 31;
  const int hi  = lane >> 5;
  const int n0  = qt * 32;

  const u16* qb = Q  + (size_t)bh * NPAD * HD;
  const u16* kb = K  + (size_t)bh * NPAD * HD;
  const u16* vb = Vt + (size_t)bh * HD * NPAD;

  s16x8 qf[4];
#pragma unroll
  for(int dt=0; dt<4; dt++)
    qf[dt] = *reinterpret_cast<const s16x8*>(qb + (size_t)(n0+col)*HD + dt*16 + hi*8);

  f32x16 accO[2];
#pragma unroll
  for(int i=0;i<16;i++){ accO[0][i]=0.f; accO[1][i]=0.f; }
  float m_run = -1e30f, l_run = 0.f;

  s16x8 kfA[8], kfB[8], vf[8];

#define LOADK(dst, KJ) { \
  const u16* kr0_ = kb + (size_t)((KJ) + col)*HD + hi*8;      \
  const u16* kr1_ = kb + (size_t)((KJ) + 32 + col)*HD + hi*8; \
  _Pragma("unroll") \
  for(int dt_=0; dt_<4; dt_++){ \
    dst[dt_]   = *reinterpret_cast<const s16x8*>(kr0_ + dt_*16); \
    dst[4+dt_] = *reinterpret_cast<const s16x8*>(kr1_ + dt_*16); } }

#define LOADV(dst, KJ) { \
  const u16* vr0_ = vb + (size_t)col*NPAD + (KJ) + hi*8; \
  const u16* vr1_ = vr0_ + (size_t)32*NPAD; \
  _Pragma("unroll") \
  for(int kh_=0; kh_<4; kh_++){ \
    dst[kh_]   = *reinterpret_cast<const s16x8*>(vr0_ + kh_*16); \
    dst[4+kh_] = *reinterpret_cast<const s16x8*>(vr1_ + kh_*16); } }

#define PROCESS(KJ, KF, VF) { \
  f32x16 St[2]; \
  __builtin_amdgcn_s_setprio(1); \
  _Pragma("unroll") \
  for(int s_=0;s_<2;s_++){ \
    _Pragma("unroll") for(int i_=0;i_<16;i_++) St[s_][i_]=0.f; \
    _Pragma("unroll") \
    for(int dt_=0;dt_<4;dt_++) \
      St[s_] = __builtin_amdgcn_mfma_f32_32x32x16_bf16(KF[s_*4+dt_], qf[dt_], St[s_], 0,0,0); \
  } \
  __builtin_amdgcn_s_setprio(0); \
  float p[32]; \
  if((KJ) + 64 <= SEQ){ \
    _Pragma("unroll") for(int i_=0;i_<32;i_++) p[i_] = St[i_>>4][i_&15]; \
  } else { \
    _Pragma("unroll") \
    for(int s_=0;s_<2;s_++) \
      _Pragma("unroll") \
      for(int r_=0;r_<16;r_++){ \
        int k_ = (KJ) + s_*32 + (r_&3) + 8*(r_>>2) + 4*hi; \
        p[s_*16+r_] = (k_ < SEQ) ? St[s_][r_] : -1e30f; \
      } \
  } \
  float red[16]; \
  _Pragma("unroll") for(int i_=0;i_<16;i_++) red[i_] = fmaxf(p[i_], p[i_+16]); \
  _Pragma("unroll") \
  for(int s2_=8;s2_>=1;s2_>>=1) \
    _Pragma("unroll") for(int i_=0;i_<8;i_++) if(i_<s2_) red[i_] = fmaxf(red[i_], red[i_+s2_]); \
  float mx = fmaxf(red[0], __shfl_xor(red[0], 32)); \
  if(!__all(mx <= m_run + 8.f)){   /* defer-max (T13) */ \
    float mnew = fmaxf(m_run, mx); \
    float alpha = exp2f(m_run - mnew); \
    m_run = mnew; \
    l_run *= alpha; \
    _Pragma("unroll") for(int i_=0;i_<16;i_++){ accO[0][i_]*=alpha; accO[1][i_]*=alpha; } \
  } \
  _Pragma("unroll") for(int i_=0;i_<32;i_++) p[i_] = exp2f(p[i_] - m_run); \
  float sr[16]; \
  _Pragma("unroll") for(int i_=0;i_<16;i_++) sr[i_] = p[i_] + p[i_+16]; \
  _Pragma("unroll") \
  for(int s2_=8;s2_>=1;s2_>>=1) \
    _Pragma("unroll") for(int i_=0;i_<8;i_++) if(i_<s2_) sr[i_] += sr[i_+s2_]; \
  l_run += sr[0] + __shfl_xor(sr[0], 32); \
  union PF { u32 w[4]; s16x8 v; } pf[4]; \
  _Pragma("unroll") \
  for(int s_=0;s_<2;s_++){ \
    _Pragma("unroll") \
    for(int hh_=0; hh_<2; hh_++){ \
      const int b0_ = s_*16 + hh_*8; \
      u32 w0_ = cvt_pk_bf16(p[b0_+0], p[b0_+1]); \
      u32 w1_ = cvt_pk_bf16(p[b0_+2], p[b0_+3]); \
      u32 w2_ = cvt_pk_bf16(p[b0_+4], p[b0_+5]); \
      u32 w3_ = cvt_pk_bf16(p[b0_+6], p[b0_+7]); \
      auto r02_ = __builtin_amdgcn_permlane32_swap(w0_, w2_, false, false); \
      auto r13_ = __builtin_amdgcn_permlane32_swap(w1_, w3_, false, false); \
      pf[s_*2+hh_].w[0] = r02_[0]; \
      pf[s_*2+hh_].w[1] = r13_[0]; \
      pf[s_*2+hh_].w[2] = r02_[1]; \
      pf[s_*2+hh_].w[3] = r13_[1]; \
    } \
  } \
  __builtin_amdgcn_s_setprio(1); \
  _Pragma("unroll") \
  for(int dt_=0; dt_<2; dt_++) \
    _Pragma("unroll") \
    for(int kh_=0; kh_<4; kh_++) \
      accO[dt_] = __builtin_amdgcn_mfma_f32_32x32x16_bf16(VF[dt_*4+kh_], pf[kh_].v, accO[dt_], 0,0,0); \
  __builtin_amdgcn_s_setprio(0); \
}

  LOADK(kfA, 0);
  for(int kt = 0; kt < NKT64; kt += 2){
    const int kj0 = kt * 64;
    __builtin_amdgcn_s_barrier();           // lockstep for L1 sharing (no vmcnt drain)
    LOADV(vf, kj0);
    LOADK(kfB, kj0 + 64);
    PROCESS(kj0, kfA, vf);
    __builtin_amdgcn_s_barrier();
    LOADV(vf, kj0 + 64);
    if(kt + 2 < NKT64) LOADK(kfA, kj0 + 128);
    PROCESS(kj0 + 64, kfB, vf);
  }

  // ---- epilogue ----
  const int n = n0 + col;
  if(wr && n < SEQ){
    float inv = 1.0f / l_run;
    const int b = bh >> 4, h = bh & 15;
    u16* orow = O + ((size_t)(b*SEQ + n))*CH + h*HD;
#pragma unroll
    for(int dt=0; dt<2; dt++)
#pragma unroll
      for(int qd=0; qd<4; qd++){
        u16x4 ov;
#pragma unroll
        for(int j=0;j<4;j++) ov[j] = f2bf(accO[dt][qd*4+j]*inv);
        *reinterpret_cast<u16x4*>(orow + dt*32 + qd*8 + hi*4) = ov;
      }
  }
}

extern "C" void kernel_launch(void* const* d_in, const int* in_sizes, int n_in,
                              void* d_out, int out_size, void* d_ws, size_t ws_size,
                              hipStream_t stream)
{
  const float* tokens = (const float*)d_in[0];
  const float* qkv_w  = (const float*)d_in[1];
  const float* qkv_b  = (const float*)d_in[2];
  const float* proj_w = (const float*)d_in[3];
  const float* proj_b = (const float*)d_in[4];
  float* out = (float*)d_out;

  char* ws = (char*)d_ws;
  u16* Xbf   = (u16*)(ws);              // MPAD*1024*2        = 11,272,192 B
  u16* Wqkv  = (u16*)(ws + 11272192);   // 3072*1024*2        =  6,291,456
  u16* Wproj = (u16*)(ws + 17563648);   // 1024*1024*2        =  2,097,152
  u16* Qb    = (u16*)(ws + 19660800);   // 64*1408*64*2       = 11,534,336
  u16* Kb    = (u16*)(ws + 31195136);
  u16* Vb    = (u16*)(ws + 42729472);
  u16* Vt    = (u16*)(ws + 54263808);
  u16* AttO  = (u16*)(ws + 65798144);   // MPAD*1024*2 ; end ~77 MB

  k_cast_tokens<<<dim3((MPAD*CH)/256), 256, 0, stream>>>(tokens, Xbf);
  k_cast<<<dim3((3*CH*CH)/256), 256, 0, stream>>>(qkv_w, Wqkv, 3*CH*CH);
  k_cast<<<dim3((CH*CH)/256),   256, 0, stream>>>(proj_w, Wproj, CH*CH);

  k_gemm128<0,128><<<dim3(1056), 256, 0, stream>>>(Xbf, Wqkv, qkv_b, Qb, Kb, Vb, nullptr);
  k_transpose_v<<<dim3(64, NPAD/64), 256, 0, stream>>>(Vb, Vt);
  k_attn4<<<dim3(704), 256, 0, stream>>>(Qb, Kb, Vt, AttO);
  k_gemm128<1,64><<<dim3(704), 256, 0, stream>>>(AttO, Wproj, proj_b, nullptr, nullptr, nullptr, out);
}

// Round 5
// 253.577 us; speedup vs baseline: 1.2324x; 1.2324x over previous
//
#include <hip/hip_runtime.h>
#include <hip/hip_bf16.h>

typedef short s16x8 __attribute__((ext_vector_type(8)));
typedef float f32x4 __attribute__((ext_vector_type(4)));
typedef float f32x16 __attribute__((ext_vector_type(16)));
typedef unsigned short u16;
typedef unsigned int   u32;
typedef u16 u16x4 __attribute__((ext_vector_type(4)));

#define SEQ  1370
#define CH   1024
#define NH   16
#define HD   64
#define BN   5480      // 4*1370
#define MPAD 5504      // 43*128
#define NPAD 1408      // 22*64
#define NQT  43        // ceil(1370/32)
#define NKT64 22       // NPAD/64

// log2(e) folded into q scale: exp(x) = exp2(x*log2e)
#define QSCALE 0.18033688f   // 0.125 * 1.44269504089

__device__ __forceinline__ u16 f2bf(float f){
  union { float f; unsigned u; } v; v.f = f;
  unsigned u = v.u;
  return (u16)((u + 0x7FFFu + ((u >> 16) & 1u)) >> 16);   // RNE
}

__device__ __forceinline__ u32 cvt_pk_bf16(float lo, float hi){
  u32 r;
  asm("v_cvt_pk_bf16_f32 %0, %1, %2" : "=v"(r) : "v"(lo), "v"(hi));
  return r;
}

#define GLOAD16(gp, lp) __builtin_amdgcn_global_load_lds( \
    (const __attribute__((address_space(1))) void*)(gp), \
    (__attribute__((address_space(3))) void*)(lp), 16, 0, 0)

// ---- casts ----
__global__ __launch_bounds__(256) void k_cast_tokens(const float* __restrict__ in, u16* __restrict__ out){
  int i = blockIdx.x * 256 + threadIdx.x;
  if(i >= MPAD*CH) return;
  int row = i >> 10;
  out[i] = (row < BN) ? f2bf(in[i]) : (u16)0;   // zero-pad M tail
}

__global__ __launch_bounds__(256) void k_cast(const float* __restrict__ in, u16* __restrict__ out, int n){
  int i = blockIdx.x * 256 + threadIdx.x;
  if(i < n) out[i] = f2bf(in[i]);
}

// ---- m97-structure NT GEMM: 128xNT tile, BK=32, global_load_lds, 4 waves ----
// MODE 0 (NT=128): QKV epilogue; grid 1056 (8 XCD x 132), region 11x x 12y
// MODE 1 (NT=64):  proj epilogue; grid 704  (8 XCD x 88),  region 11x x 8y
template<int MODE, int NT>
__global__ __launch_bounds__(256,2) void k_gemm128(
    const u16* __restrict__ A, const u16* __restrict__ Bw, const float* __restrict__ bias,
    u16* __restrict__ q, u16* __restrict__ kk, u16* __restrict__ vv, float* __restrict__ out)
{
  constexpr int NF = NT/32;
  __shared__ u16 As[128*32];     // linear — global_load_lds needs linear dest
  __shared__ u16 Bs[NT*32];
  const int t = threadIdx.x;
  const int lane = t & 63;
  const int w = t >> 6;
  const int wm = w >> 1, wn = w & 1;
  const int g = lane >> 4, lr = lane & 15;

  const int bid = blockIdx.x;
  const int xcd = bid & 7, idx = bid >> 3;
  const int xr = xcd & 3, yr = xcd >> 2;
  constexpr int YLOC = (MODE == 0) ? 12 : 8;
  const int x = xr*11 + idx % 11;
  const int y = yr*YLOC + idx / 11;
  if(x >= MPAD/128) return;
  const int m0 = x*128, n0 = y*NT;

  const u16* ga0 = A  + (size_t)(m0 + (t >> 2)) * 1024 + (t & 3) * 8;
  const u16* gb0 = Bw + (size_t)(n0 + (t >> 2)) * 1024 + (t & 3) * 8;
  u16* law = As + w * 512;
  u16* lbw = Bs + w * 512;

  f32x4 z = {0.f,0.f,0.f,0.f};
  f32x4 acc[4][NF];
#pragma unroll
  for(int mf=0;mf<4;mf++)
#pragma unroll
    for(int nf=0;nf<NF;nf++) acc[mf][nf] = z;

  for(int k0 = 0; k0 < 1024; k0 += 32){
    GLOAD16(ga0 + k0,             law);
    GLOAD16(ga0 + k0 + 64*1024,   law + 2048);
    GLOAD16(gb0 + k0,             lbw);
    if constexpr (NT == 128) GLOAD16(gb0 + k0 + 64*1024, lbw + 2048);
    __syncthreads();
    s16x8 af[4], bf[NF];
#pragma unroll
    for(int mf = 0; mf < 4; mf++)
      af[mf] = *reinterpret_cast<const s16x8*>(&As[(wm*64 + mf*16 + lr)*32 + g*8]);
#pragma unroll
    for(int nf = 0; nf < NF; nf++)
      bf[nf] = *reinterpret_cast<const s16x8*>(&Bs[(wn*16*NF + nf*16 + lr)*32 + g*8]);
#pragma unroll
    for(int mf = 0; mf < 4; mf++)
#pragma unroll
      for(int nf = 0; nf < NF; nf++)
        acc[mf][nf] = __builtin_amdgcn_mfma_f32_16x16x32_bf16(af[mf], bf[nf], acc[mf][nf], 0,0,0);
    __syncthreads();
  }

#pragma unroll
  for(int mf = 0; mf < 4; mf++){
#pragma unroll
    for(int nf = 0; nf < NF; nf++){
      int colc = n0 + wn*16*NF + nf*16 + lr;
      float bb = bias[colc];
#pragma unroll
      for(int r = 0; r < 4; r++){
        int row = m0 + wm*64 + mf*16 + g*4 + r;   // C/D: col=lane&15, row=(lane>>4)*4+reg
        if(row >= BN) continue;
        float v = acc[mf][nf][r] + bb;
        if constexpr (MODE == 0){
          int b = row / SEQ, n = row - b*SEQ;
          int tt = colc >> 10, h = (colc >> 6) & 15, cc = colc & 63;
          size_t bh = (size_t)(b*NH + h);
          if(tt == 0)      q [(bh*NPAD + n)*HD + cc] = f2bf(v * QSCALE);
          else if(tt == 1) kk[(bh*NPAD + n)*HD + cc] = f2bf(v);
          else             vv[(bh*NPAD + n)*HD + cc] = f2bf(v);
        } else {
          out[(size_t)row * CH + colc] = v;
        }
      }
    }
  }
}

// ---- V[bh][n][cc] -> Vt[bh][cc][n], zero-fills n in [SEQ,NPAD) ----
__global__ __launch_bounds__(256) void k_transpose_v(const u16* __restrict__ V, u16* __restrict__ Vt){
  __shared__ u16 Ts[64][80];
  const int bh = blockIdx.x, nt = blockIdx.y;
  const int n0 = nt * 64;
  const int t = threadIdx.x;
  const int row = t >> 3;
  const int c8  = (t & 7) * 8;
  const u16* vb = V + (size_t)bh * NPAD * HD;
  for(int i = 0; i < 2; i++){
    int r = row + i*32;
    int n = n0 + r;
    s16x8 val = {0,0,0,0,0,0,0,0};
    if(n < SEQ) val = *reinterpret_cast<const s16x8*>(vb + (size_t)n*HD + c8);
    *reinterpret_cast<s16x8*>(&Ts[r][c8]) = val;
  }
  __syncthreads();
  u16* vtb = Vt + (size_t)bh * HD * NPAD;
  for(int i = 0; i < 2; i++){
    int cc = row + i*32;
    s16x8 o;
    for(int j = 0; j < 8; j++) o[j] = Ts[c8 + j][cc];
    *reinterpret_cast<s16x8*>(vtb + (size_t)cc*NPAD + n0 + c8) = o;
  }
}

// ---- flash attention v5: register-light inline loads (round-2 style, no spill)
// + 4 waves/block sharing bh + bijective XCD swizzle + raw s_barrier lockstep
// + exp2 softmax, defer-max (T13), setprio (T5). ----
__global__ __launch_bounds__(256,4) void k_attn5(
    const u16* __restrict__ Q, const u16* __restrict__ K,
    const u16* __restrict__ Vt, u16* __restrict__ O)
{
  const int bid = blockIdx.x;                 // 0..703
  const int swz = (bid & 7)*88 + (bid >> 3);  // bijective: 704 = 8*88
  const int bh = swz / 11;                    // 8 bh per XCD -> K/V 2.9MB in its L2
  const int qg = swz - bh*11;
  const int w = threadIdx.x >> 6;
  int qt = qg*4 + w;
  const bool wr = (qt < NQT);
  if(!wr) qt = NQT - 1;                       // dup wave: recompute, no store
  const int lane = threadIdx.x & 63;
  const int col = lane & 31;
  const int hi  = lane >> 5;
  const int n0  = qt * 32;

  const u16* qb = Q  + (size_t)bh * NPAD * HD;
  const u16* kb = K  + (size_t)bh * NPAD * HD;
  const u16* vb = Vt + (size_t)bh * HD * NPAD;

  s16x8 qf[4];
#pragma unroll
  for(int dt=0; dt<4; dt++)
    qf[dt] = *reinterpret_cast<const s16x8*>(qb + (size_t)(n0+col)*HD + dt*16 + hi*8);

  f32x16 accO[2];
#pragma unroll
  for(int i=0;i<16;i++){ accO[0][i]=0.f; accO[1][i]=0.f; }
  float m_run = -1e30f, l_run = 0.f;

  for(int kt = 0; kt < NKT64; kt++){
    const int kj0 = kt * 64;
    __builtin_amdgcn_s_barrier();       // lockstep: 4 waves stream same K/V lines
    // ---- QK^T (swapped), K loaded inline ----
    f32x16 St[2];
    __builtin_amdgcn_s_setprio(1);
#pragma unroll
    for(int s=0;s<2;s++){
#pragma unroll
      for(int i=0;i<16;i++) St[s][i]=0.f;
      const u16* krow = kb + (size_t)(kj0 + s*32 + col)*HD + hi*8;
#pragma unroll
      for(int dt=0;dt<4;dt++){
        s16x8 kf = *reinterpret_cast<const s16x8*>(krow + dt*16);
        St[s] = __builtin_amdgcn_mfma_f32_32x32x16_bf16(kf, qf[dt], St[s], 0,0,0);
      }
    }
    __builtin_amdgcn_s_setprio(0);
    // ---- mask (wave-uniform branch) ----
    float p[32];
    if(kj0 + 64 <= SEQ){
#pragma unroll
      for(int i=0;i<32;i++) p[i] = St[i>>4][i&15];
    } else {
#pragma unroll
      for(int s=0;s<2;s++)
#pragma unroll
        for(int r=0;r<16;r++){
          int k = kj0 + s*32 + (r&3) + 8*(r>>2) + 4*hi;
          p[s*16+r] = (k < SEQ) ? St[s][r] : -1e30f;
        }
    }
    // ---- online softmax (base-2), defer-max ----
    float red[16];
#pragma unroll
    for(int i=0;i<16;i++) red[i] = fmaxf(p[i], p[i+16]);
#pragma unroll
    for(int s2=8;s2>=1;s2>>=1)
#pragma unroll
      for(int i=0;i<8;i++) if(i<s2) red[i] = fmaxf(red[i], red[i+s2]);
    float mx = fmaxf(red[0], __shfl_xor(red[0], 32));
    if(!__all(mx <= m_run + 8.f)){   // defer-max (T13)
      float mnew = fmaxf(m_run, mx);
      float alpha = exp2f(m_run - mnew);
      m_run = mnew;
      l_run *= alpha;
#pragma unroll
      for(int i=0;i<16;i++){ accO[0][i]*=alpha; accO[1][i]*=alpha; }
    }
#pragma unroll
    for(int i=0;i<32;i++) p[i] = exp2f(p[i] - m_run);
    float sr[16];
#pragma unroll
    for(int i=0;i<16;i++) sr[i] = p[i] + p[i+16];
#pragma unroll
    for(int s2=8;s2>=1;s2>>=1)
#pragma unroll
      for(int i=0;i<8;i++) if(i<s2) sr[i] += sr[i+s2];
    l_run += sr[0] + __shfl_xor(sr[0], 32);
    // ---- P repack (T12) ----
    union PF { u32 w[4]; s16x8 v; } pf[4];
#pragma unroll
    for(int s=0;s<2;s++){
#pragma unroll
      for(int hh=0; hh<2; hh++){
        const int b0 = s*16 + hh*8;
        u32 w0 = cvt_pk_bf16(p[b0+0], p[b0+1]);
        u32 w1 = cvt_pk_bf16(p[b0+2], p[b0+3]);
        u32 w2 = cvt_pk_bf16(p[b0+4], p[b0+5]);
        u32 w3 = cvt_pk_bf16(p[b0+6], p[b0+7]);
        auto r02 = __builtin_amdgcn_permlane32_swap(w0, w2, false, false);
        auto r13 = __builtin_amdgcn_permlane32_swap(w1, w3, false, false);
        pf[s*2+hh].w[0] = r02[0];
        pf[s*2+hh].w[1] = r13[0];
        pf[s*2+hh].w[2] = r02[1];
        pf[s*2+hh].w[3] = r13[1];
      }
    }
    // ---- PV, V loaded inline ----
    __builtin_amdgcn_s_setprio(1);
#pragma unroll
    for(int kh=0; kh<4; kh++){
      const u16* vr = vb + (size_t)col*NPAD + kj0 + kh*16 + hi*8;
#pragma unroll
      for(int dt=0; dt<2; dt++){
        s16x8 vf = *reinterpret_cast<const s16x8*>(vr + (size_t)dt*32*NPAD);
        accO[dt] = __builtin_amdgcn_mfma_f32_32x32x16_bf16(vf, pf[kh].v, accO[dt], 0,0,0);
      }
    }
    __builtin_amdgcn_s_setprio(0);
  }

  // ---- epilogue ----
  const int n = n0 + col;
  if(wr && n < SEQ){
    float inv = 1.0f / l_run;
    const int b = bh >> 4, h = bh & 15;
    u16* orow = O + ((size_t)(b*SEQ + n))*CH + h*HD;
#pragma unroll
    for(int dt=0; dt<2; dt++)
#pragma unroll
      for(int qd=0; qd<4; qd++){
        u16x4 ov;
#pragma unroll
        for(int j=0;j<4;j++) ov[j] = f2bf(accO[dt][qd*4+j]*inv);
        *reinterpret_cast<u16x4*>(orow + dt*32 + qd*8 + hi*4) = ov;
      }
  }
}

extern "C" void kernel_launch(void* const* d_in, const int* in_sizes, int n_in,
                              void* d_out, int out_size, void* d_ws, size_t ws_size,
                              hipStream_t stream)
{
  const float* tokens = (const float*)d_in[0];
  const float* qkv_w  = (const float*)d_in[1];
  const float* qkv_b  = (const float*)d_in[2];
  const float* proj_w = (const float*)d_in[3];
  const float* proj_b = (const float*)d_in[4];
  float* out = (float*)d_out;

  char* ws = (char*)d_ws;
  u16* Xbf   = (u16*)(ws);              // MPAD*1024*2        = 11,272,192 B
  u16* Wqkv  = (u16*)(ws + 11272192);   // 3072*1024*2        =  6,291,456
  u16* Wproj = (u16*)(ws + 17563648);   // 1024*1024*2        =  2,097,152
  u16* Qb    = (u16*)(ws + 19660800);   // 64*1408*64*2       = 11,534,336
  u16* Kb    = (u16*)(ws + 31195136);
  u16* Vb    = (u16*)(ws + 42729472);
  u16* Vt    = (u16*)(ws + 54263808);
  u16* AttO  = (u16*)(ws + 65798144);   // MPAD*1024*2 ; end ~77 MB

  k_cast_tokens<<<dim3((MPAD*CH)/256), 256, 0, stream>>>(tokens, Xbf);
  k_cast<<<dim3((3*CH*CH)/256), 256, 0, stream>>>(qkv_w, Wqkv, 3*CH*CH);
  k_cast<<<dim3((CH*CH)/256),   256, 0, stream>>>(proj_w, Wproj, CH*CH);

  k_gemm128<0,128><<<dim3(1056), 256, 0, stream>>>(Xbf, Wqkv, qkv_b, Qb, Kb, Vb, nullptr);
  k_transpose_v<<<dim3(64, NPAD/64), 256, 0, stream>>>(Vb, Vt);
  k_attn5<<<dim3(704), 256, 0, stream>>>(Qb, Kb, Vt, AttO);
  k_gemm128<1,64><<<dim3(704), 256, 0, stream>>>(AttO, Wproj, proj_b, nullptr, nullptr, nullptr, out);
}

// Round 6
// 187.043 us; speedup vs baseline: 1.6708x; 1.3557x over previous
//
#include <hip/hip_runtime.h>
#include <hip/hip_bf16.h>

typedef short s16x8 __attribute__((ext_vector_type(8)));
typedef float f32x4 __attribute__((ext_vector_type(4)));
typedef float f32x16 __attribute__((ext_vector_type(16)));
typedef unsigned short u16;
typedef unsigned int   u32;
typedef u16 u16x4 __attribute__((ext_vector_type(4)));

#define SEQ  1370
#define CH   1024
#define NH   16
#define HD   64
#define BN   5480      // 4*1370
#define MPAD 5504      // 43*128
#define NPAD 1408      // 44*32
#define NQT  43        // ceil(1370/32)
#define NKT64 22       // NPAD/64

// log2(e) folded into q scale: exp(x) = exp2(x*log2e)
#define QSCALE 0.18033688f   // 0.125 * 1.44269504089

// Fragment-linear layouts (all loads in k_attn are base + lane*16B, fully coalesced):
//  Qf/Kf[bh][gg][dt][hi][col][8]  : gg=n>>5 (44), dt=cc>>4 (4), hi=(cc>>3)&1, col=n&31, e=cc&7
//  Vf[bh][kt][kh][dtv][hi][col][8]: kt=n>>6 (22), kh=(n>>4)&3, hi=(n>>3)&1, e=n&7, dtv=cc>>5, col=cc&31

__device__ __forceinline__ u16 f2bf(float f){
  union { float f; unsigned u; } v; v.f = f;
  unsigned u = v.u;
  return (u16)((u + 0x7FFFu + ((u >> 16) & 1u)) >> 16);   // RNE
}

__device__ __forceinline__ u32 cvt_pk_bf16(float lo, float hi){
  u32 r;
  asm("v_cvt_pk_bf16_f32 %0, %1, %2" : "=v"(r) : "v"(lo), "v"(hi));
  return r;
}

#define GLOAD16(gp, lp) __builtin_amdgcn_global_load_lds( \
    (const __attribute__((address_space(1))) void*)(gp), \
    (__attribute__((address_space(3))) void*)(lp), 16, 0, 0)

// ---- casts ----
__global__ __launch_bounds__(256) void k_cast_tokens(const float* __restrict__ in, u16* __restrict__ out){
  int i = blockIdx.x * 256 + threadIdx.x;
  if(i >= MPAD*CH) return;
  int row = i >> 10;
  out[i] = (row < BN) ? f2bf(in[i]) : (u16)0;   // zero-pad M tail
}

__global__ __launch_bounds__(256) void k_cast(const float* __restrict__ in, u16* __restrict__ out, int n){
  int i = blockIdx.x * 256 + threadIdx.x;
  if(i < n) out[i] = f2bf(in[i]);
}

// ---- m97-structure NT GEMM: 128xNT tile, BK=32, global_load_lds, 4 waves ----
// MODE 0 (NT=128): QKV epilogue -> fragment-linear Qf/Kf/Vf; grid 1056
// MODE 1 (NT=64):  proj epilogue (fp32 + bias); grid 704
template<int MODE, int NT>
__global__ __launch_bounds__(256,2) void k_gemm128(
    const u16* __restrict__ A, const u16* __restrict__ Bw, const float* __restrict__ bias,
    u16* __restrict__ q, u16* __restrict__ kk, u16* __restrict__ vv, float* __restrict__ out)
{
  constexpr int NF = NT/32;
  __shared__ u16 As[128*32];     // linear — global_load_lds needs linear dest
  __shared__ u16 Bs[NT*32];
  const int t = threadIdx.x;
  const int lane = t & 63;
  const int w = t >> 6;
  const int wm = w >> 1, wn = w & 1;
  const int g = lane >> 4, lr = lane & 15;

  const int bid = blockIdx.x;
  const int xcd = bid & 7, idx = bid >> 3;
  const int xr = xcd & 3, yr = xcd >> 2;
  constexpr int YLOC = (MODE == 0) ? 12 : 8;
  const int x = xr*11 + idx % 11;
  const int y = yr*YLOC + idx / 11;
  if(x >= MPAD/128) return;
  const int m0 = x*128, n0 = y*NT;

  const u16* ga0 = A  + (size_t)(m0 + (t >> 2)) * 1024 + (t & 3) * 8;
  const u16* gb0 = Bw + (size_t)(n0 + (t >> 2)) * 1024 + (t & 3) * 8;
  u16* law = As + w * 512;
  u16* lbw = Bs + w * 512;

  f32x4 z = {0.f,0.f,0.f,0.f};
  f32x4 acc[4][NF];
#pragma unroll
  for(int mf=0;mf<4;mf++)
#pragma unroll
    for(int nf=0;nf<NF;nf++) acc[mf][nf] = z;

  for(int k0 = 0; k0 < 1024; k0 += 32){
    GLOAD16(ga0 + k0,             law);
    GLOAD16(ga0 + k0 + 64*1024,   law + 2048);
    GLOAD16(gb0 + k0,             lbw);
    if constexpr (NT == 128) GLOAD16(gb0 + k0 + 64*1024, lbw + 2048);
    __syncthreads();
    s16x8 af[4], bf[NF];
#pragma unroll
    for(int mf = 0; mf < 4; mf++)
      af[mf] = *reinterpret_cast<const s16x8*>(&As[(wm*64 + mf*16 + lr)*32 + g*8]);
#pragma unroll
    for(int nf = 0; nf < NF; nf++)
      bf[nf] = *reinterpret_cast<const s16x8*>(&Bs[(wn*16*NF + nf*16 + lr)*32 + g*8]);
#pragma unroll
    for(int mf = 0; mf < 4; mf++)
#pragma unroll
      for(int nf = 0; nf < NF; nf++)
        acc[mf][nf] = __builtin_amdgcn_mfma_f32_16x16x32_bf16(af[mf], bf[nf], acc[mf][nf], 0,0,0);
    __syncthreads();
  }

#pragma unroll
  for(int mf = 0; mf < 4; mf++){
#pragma unroll
    for(int nf = 0; nf < NF; nf++){
      int colc = n0 + wn*16*NF + nf*16 + lr;
      float bb = bias[colc];
#pragma unroll
      for(int r = 0; r < 4; r++){
        int row = m0 + wm*64 + mf*16 + g*4 + r;   // C/D: col=lane&15, row=(lane>>4)*4+reg
        if(row >= BN) continue;
        float v = acc[mf][nf][r] + bb;
        if constexpr (MODE == 0){
          int b = row / SEQ, n = row - b*SEQ;
          int tt = colc >> 10, h = (colc >> 6) & 15, cc = colc & 63;
          int bh = b*NH + h;
          if(tt == 2){
            int ktv = n >> 6, kh = (n >> 4) & 3, hiv = (n >> 3) & 1, e = n & 7;
            int dtv = cc >> 5, colr = cc & 31;
            vv[(size_t)((((bh*22 + ktv)*4 + kh)*2 + dtv)*2 + hiv)*256 + colr*8 + e] = f2bf(v);
          } else {
            int gg = n >> 5, colr = n & 31;
            int dtv = cc >> 4, hiq = (cc >> 3) & 1, e = cc & 7;
            size_t fidx = (size_t)(((bh*44 + gg)*4 + dtv)*2 + hiq)*256 + colr*8 + e;
            if(tt == 0) q [fidx] = f2bf(v * QSCALE);
            else        kk[fidx] = f2bf(v);
          }
        } else {
          out[(size_t)row * CH + colc] = v;
        }
      }
    }
  }
}

// ---- flash attention v6: fragment-linear coalesced loads (1KB/instr), 4 waves
// share bh, bijective XCD swizzle, raw s_barrier lockstep, exp2 softmax,
// defer-max (T13), early-V (T14), setprio (T5). ----
__global__ __launch_bounds__(256,3) void k_attn6(
    const u16* __restrict__ Qf, const u16* __restrict__ Kf,
    const u16* __restrict__ Vf, u16* __restrict__ O)
{
  const int bid = blockIdx.x;                 // 0..703
  const int swz = (bid & 7)*88 + (bid >> 3);  // bijective: 704 = 8*88
  const int bh = swz / 11;                    // 8 bh per XCD -> K/V in its L2
  const int qg = swz - bh*11;
  const int w = threadIdx.x >> 6;
  int qt = qg*4 + w;
  const bool wr = (qt < NQT);
  if(!wr) qt = NQT - 1;                       // dup wave: recompute, no store
  const int lane = threadIdx.x & 63;
  const int col = lane & 31;
  const int hi  = lane >> 5;
  const int n0  = qt * 32;
  const size_t lofs = hi*256 + col*8;         // per-lane 16B slot within a 1KB fragment

  s16x8 qf[4];
  {
    const u16* qfb = Qf + (size_t)(bh*44 + qt)*2048 + lofs;
#pragma unroll
    for(int dt=0; dt<4; dt++)
      qf[dt] = *reinterpret_cast<const s16x8*>(qfb + dt*512);
  }
  const u16* kfb = Kf + (size_t)bh*44*2048 + lofs;
  const u16* vfb = Vf + (size_t)bh*22*4096 + lofs;

  f32x16 accO[2];
#pragma unroll
  for(int i=0;i<16;i++){ accO[0][i]=0.f; accO[1][i]=0.f; }
  float m_run = -1e30f, l_run = 0.f;

  for(int kt = 0; kt < NKT64; kt++){
    const int kj0 = kt * 64;
    __builtin_amdgcn_s_barrier();       // lockstep: 4 waves stream same K/V lines
    // ---- QK^T (swapped), coalesced K fragment loads ----
    f32x16 St[2];
    __builtin_amdgcn_s_setprio(1);
#pragma unroll
    for(int s=0;s<2;s++){
#pragma unroll
      for(int i=0;i<16;i++) St[s][i]=0.f;
      const u16* kr = kfb + (size_t)(kt*2+s)*2048;
#pragma unroll
      for(int dt=0;dt<4;dt++){
        s16x8 kf = *reinterpret_cast<const s16x8*>(kr + dt*512);
        St[s] = __builtin_amdgcn_mfma_f32_32x32x16_bf16(kf, qf[dt], St[s], 0,0,0);
      }
    }
    __builtin_amdgcn_s_setprio(0);
    // ---- early V issue (T14): latency hides under softmax ----
    s16x8 vfr[8];
    {
      const u16* vr = vfb + (size_t)kt*4096;
#pragma unroll
      for(int i=0;i<8;i++)
        vfr[i] = *reinterpret_cast<const s16x8*>(vr + i*512);
    }
    // ---- mask (wave-uniform branch) ----
    float p[32];
    if(kj0 + 64 <= SEQ){
#pragma unroll
      for(int i=0;i<32;i++) p[i] = St[i>>4][i&15];
    } else {
#pragma unroll
      for(int s=0;s<2;s++)
#pragma unroll
        for(int r=0;r<16;r++){
          int k = kj0 + s*32 + (r&3) + 8*(r>>2) + 4*hi;
          p[s*16+r] = (k < SEQ) ? St[s][r] : -1e30f;
        }
    }
    // ---- online softmax (base-2), defer-max ----
    float red[16];
#pragma unroll
    for(int i=0;i<16;i++) red[i] = fmaxf(p[i], p[i+16]);
#pragma unroll
    for(int s2=8;s2>=1;s2>>=1)
#pragma unroll
      for(int i=0;i<8;i++) if(i<s2) red[i] = fmaxf(red[i], red[i+s2]);
    float mx = fmaxf(red[0], __shfl_xor(red[0], 32));
    if(!__all(mx <= m_run + 8.f)){   // defer-max (T13)
      float mnew = fmaxf(m_run, mx);
      float alpha = exp2f(m_run - mnew);
      m_run = mnew;
      l_run *= alpha;
#pragma unroll
      for(int i=0;i<16;i++){ accO[0][i]*=alpha; accO[1][i]*=alpha; }
    }
#pragma unroll
    for(int i=0;i<32;i++) p[i] = exp2f(p[i] - m_run);
    float sr[16];
#pragma unroll
    for(int i=0;i<16;i++) sr[i] = p[i] + p[i+16];
#pragma unroll
    for(int s2=8;s2>=1;s2>>=1)
#pragma unroll
      for(int i=0;i<8;i++) if(i<s2) sr[i] += sr[i+s2];
    l_run += sr[0] + __shfl_xor(sr[0], 32);
    // ---- P repack (T12) ----
    union PF { u32 w[4]; s16x8 v; } pf[4];
#pragma unroll
    for(int s=0;s<2;s++){
#pragma unroll
      for(int hh=0; hh<2; hh++){
        const int b0 = s*16 + hh*8;
        u32 w0 = cvt_pk_bf16(p[b0+0], p[b0+1]);
        u32 w1 = cvt_pk_bf16(p[b0+2], p[b0+3]);
        u32 w2 = cvt_pk_bf16(p[b0+4], p[b0+5]);
        u32 w3 = cvt_pk_bf16(p[b0+6], p[b0+7]);
        auto r02 = __builtin_amdgcn_permlane32_swap(w0, w2, false, false);
        auto r13 = __builtin_amdgcn_permlane32_swap(w1, w3, false, false);
        pf[s*2+hh].w[0] = r02[0];
        pf[s*2+hh].w[1] = r13[0];
        pf[s*2+hh].w[2] = r02[1];
        pf[s*2+hh].w[3] = r13[1];
      }
    }
    // ---- PV from prefetched V fragments ----
    __builtin_amdgcn_s_setprio(1);
#pragma unroll
    for(int kh=0; kh<4; kh++)
#pragma unroll
      for(int dt=0; dt<2; dt++)
        accO[dt] = __builtin_amdgcn_mfma_f32_32x32x16_bf16(vfr[kh*2+dt], pf[kh].v, accO[dt], 0,0,0);
    __builtin_amdgcn_s_setprio(0);
  }

  // ---- epilogue ----
  const int n = n0 + col;
  if(wr && n < SEQ){
    float inv = 1.0f / l_run;
    const int b = bh >> 4, h = bh & 15;
    u16* orow = O + ((size_t)(b*SEQ + n))*CH + h*HD;
#pragma unroll
    for(int dt=0; dt<2; dt++)
#pragma unroll
      for(int qd=0; qd<4; qd++){
        u16x4 ov;
#pragma unroll
        for(int j=0;j<4;j++) ov[j] = f2bf(accO[dt][qd*4+j]*inv);
        *reinterpret_cast<u16x4*>(orow + dt*32 + qd*8 + hi*4) = ov;
      }
  }
}

extern "C" void kernel_launch(void* const* d_in, const int* in_sizes, int n_in,
                              void* d_out, int out_size, void* d_ws, size_t ws_size,
                              hipStream_t stream)
{
  const float* tokens = (const float*)d_in[0];
  const float* qkv_w  = (const float*)d_in[1];
  const float* qkv_b  = (const float*)d_in[2];
  const float* proj_w = (const float*)d_in[3];
  const float* proj_b = (const float*)d_in[4];
  float* out = (float*)d_out;

  char* ws = (char*)d_ws;
  u16* Xbf   = (u16*)(ws);              // MPAD*1024*2        = 11,272,192 B
  u16* Wqkv  = (u16*)(ws + 11272192);   // 3072*1024*2        =  6,291,456
  u16* Wproj = (u16*)(ws + 17563648);   // 1024*1024*2        =  2,097,152
  u16* Qfb   = (u16*)(ws + 19660800);   // 64*44*2048*2       = 11,534,336
  u16* Kfb   = (u16*)(ws + 31195136);
  u16* Vfb   = (u16*)(ws + 42729472);
  u16* AttO  = (u16*)(ws + 65798144);   // MPAD*1024*2

  k_cast_tokens<<<dim3((MPAD*CH)/256), 256, 0, stream>>>(tokens, Xbf);
  k_cast<<<dim3((3*CH*CH)/256), 256, 0, stream>>>(qkv_w, Wqkv, 3*CH*CH);
  k_cast<<<dim3((CH*CH)/256),   256, 0, stream>>>(proj_w, Wproj, CH*CH);

  k_gemm128<0,128><<<dim3(1056), 256, 0, stream>>>(Xbf, Wqkv, qkv_b, Qfb, Kfb, Vfb, nullptr);
  k_attn6<<<dim3(704), 256, 0, stream>>>(Qfb, Kfb, Vfb, AttO);
  k_gemm128<1,64><<<dim3(704), 256, 0, stream>>>(AttO, Wproj, proj_b, nullptr, nullptr, nullptr, out);
}

// Round 7
// 182.190 us; speedup vs baseline: 1.7153x; 1.0266x over previous
//
#include <hip/hip_runtime.h>
#include <hip/hip_bf16.h>

typedef short s16x8 __attribute__((ext_vector_type(8)));
typedef float f32x4 __attribute__((ext_vector_type(4)));
typedef float f32x16 __attribute__((ext_vector_type(16)));
typedef unsigned short u16;
typedef unsigned int   u32;
typedef u16 u16x4 __attribute__((ext_vector_type(4)));

#define SEQ  1370
#define CH   1024
#define NH   16
#define HD   64
#define BN   5480      // 4*1370
#define MPAD 5504      // 43*128
#define NPAD 1408      // 44*32
#define NQT  43        // ceil(1370/32)
#define NKT64 22       // NPAD/64

// log2(e) folded into q scale: exp(x) = exp2(x*log2e)
#define QSCALE 0.18033688f   // 0.125 * 1.44269504089

// Fragment-linear layouts (all loads in k_attn are base + lane*16B, fully coalesced):
//  Qf/Kf[bh][gg][dt][hi][col][8]  : gg=n>>5 (44), dt=cc>>4 (4), hi=(cc>>3)&1, col=n&31, e=cc&7
//  Vf[bh][kt][kh][dtv][hi][col][8]: kt=n>>6 (22), kh=(n>>4)&3, hi=(n>>3)&1, e=n&7, dtv=cc>>5, col=cc&31

__device__ __forceinline__ u16 f2bf(float f){
  union { float f; unsigned u; } v; v.f = f;
  unsigned u = v.u;
  return (u16)((u + 0x7FFFu + ((u >> 16) & 1u)) >> 16);   // RNE
}

__device__ __forceinline__ u32 cvt_pk_bf16(float lo, float hi){
  u32 r;
  asm("v_cvt_pk_bf16_f32 %0, %1, %2" : "=v"(r) : "v"(lo), "v"(hi));
  return r;
}

#define GLOAD16(gp, lp) __builtin_amdgcn_global_load_lds( \
    (const __attribute__((address_space(1))) void*)(gp), \
    (__attribute__((address_space(3))) void*)(lp), 16, 0, 0)

// ---- casts ----
__global__ __launch_bounds__(256) void k_cast_tokens(const float* __restrict__ in, u16* __restrict__ out){
  int i = blockIdx.x * 256 + threadIdx.x;
  if(i >= MPAD*CH) return;
  int row = i >> 10;
  out[i] = (row < BN) ? f2bf(in[i]) : (u16)0;   // zero-pad M tail
}

__global__ __launch_bounds__(256) void k_cast(const float* __restrict__ in, u16* __restrict__ out, int n){
  int i = blockIdx.x * 256 + threadIdx.x;
  if(i < n) out[i] = f2bf(in[i]);
}

// ---- NT GEMM: 128xNT tile, BK=64, global_load_lds, XOR-swizzled LDS (T2, rule #21):
// linear LDS dest + inverse-permuted GLOBAL source chunk + XOR on read -> conflict-free b128.
// MODE 0 (NT=128): QKV epilogue -> fragment-linear Qf/Kf/Vf; grid 1056
// MODE 1 (NT=64):  proj epilogue (fp32 + bias); grid 704
template<int MODE, int NT>
__global__ __launch_bounds__(256,2) void k_gemm128(
    const u16* __restrict__ A, const u16* __restrict__ Bw, const float* __restrict__ bias,
    u16* __restrict__ q, u16* __restrict__ kk_, u16* __restrict__ vv, float* __restrict__ out)
{
  constexpr int NF = NT/32;
  constexpr int BJ = NT/32;      // B staging instrs per wave (rows/32)
  __shared__ u16 As[128*64];     // [row][64], rows 128B; swizzled granule order
  __shared__ u16 Bs[NT*64];
  const int t = threadIdx.x;
  const int lane = t & 63;
  const int w = t >> 6;
  const int wm = w >> 1, wn = w & 1;
  const int g = lane >> 4, lr = lane & 15;

  const int bid = blockIdx.x;
  const int xcd = bid & 7, idx = bid >> 3;
  const int xr = xcd & 3, yr = xcd >> 2;
  constexpr int YLOC = (MODE == 0) ? 12 : 8;
  const int x = xr*11 + idx % 11;
  const int y = yr*YLOC + idx / 11;
  if(x >= MPAD/128) return;
  const int m0 = x*128, n0 = y*NT;

  // inverse-swizzled global source: thread t stages global 16B-chunk (t&7)^((t>>3)&7)
  // of row (t>>3)+j*32 into LDS granule t&7 of that row (linear dest).
  const int swc = ((t & 7) ^ ((t >> 3) & 7)) * 8;
  const u16* ga0 = A  + (size_t)(m0 + (t >> 3)) * 1024 + swc;
  const u16* gb0 = Bw + (size_t)(n0 + (t >> 3)) * 1024 + swc;

  f32x4 z = {0.f,0.f,0.f,0.f};
  f32x4 acc[4][NF];
#pragma unroll
  for(int mf=0;mf<4;mf++)
#pragma unroll
    for(int nf=0;nf<NF;nf++) acc[mf][nf] = z;

  for(int k0 = 0; k0 < 1024; k0 += 64){
#pragma unroll
    for(int j=0;j<4;j++)
      GLOAD16(ga0 + k0 + j*32*1024, As + j*2048 + w*512);
#pragma unroll
    for(int j=0;j<BJ;j++)
      GLOAD16(gb0 + k0 + j*32*1024, Bs + j*2048 + w*512);
    __syncthreads();              // vmcnt(0) drain + barrier: tiles resident
#pragma unroll
    for(int kk=0; kk<2; kk++){
      s16x8 af[4], bf[NF];
#pragma unroll
      for(int mf = 0; mf < 4; mf++)
        af[mf] = *reinterpret_cast<const s16x8*>(&As[(wm*64 + mf*16 + lr)*64 + ((kk*4+g) ^ (lr&7))*8]);
#pragma unroll
      for(int nf = 0; nf < NF; nf++)
        bf[nf] = *reinterpret_cast<const s16x8*>(&Bs[(wn*16*NF + nf*16 + lr)*64 + ((kk*4+g) ^ (lr&7))*8]);
#pragma unroll
      for(int mf = 0; mf < 4; mf++)
#pragma unroll
        for(int nf = 0; nf < NF; nf++)
          acc[mf][nf] = __builtin_amdgcn_mfma_f32_16x16x32_bf16(af[mf], bf[nf], acc[mf][nf], 0,0,0);
    }
    __syncthreads();              // all reads done before next overwrite
  }

#pragma unroll
  for(int mf = 0; mf < 4; mf++){
#pragma unroll
    for(int nf = 0; nf < NF; nf++){
      int colc = n0 + wn*16*NF + nf*16 + lr;
      float bb = bias[colc];
#pragma unroll
      for(int r = 0; r < 4; r++){
        int row = m0 + wm*64 + mf*16 + g*4 + r;   // C/D: col=lane&15, row=(lane>>4)*4+reg
        if(row >= BN) continue;
        float v = acc[mf][nf][r] + bb;
        if constexpr (MODE == 0){
          int b = row / SEQ, n = row - b*SEQ;
          int tt = colc >> 10, h = (colc >> 6) & 15, cc = colc & 63;
          int bh = b*NH + h;
          if(tt == 2){
            int ktv = n >> 6, kh = (n >> 4) & 3, hiv = (n >> 3) & 1, e = n & 7;
            int dtv = cc >> 5, colr = cc & 31;
            vv[(size_t)((((bh*22 + ktv)*4 + kh)*2 + dtv)*2 + hiv)*256 + colr*8 + e] = f2bf(v);
          } else {
            int gg = n >> 5, colr = n & 31;
            int dtv = cc >> 4, hiq = (cc >> 3) & 1, e = cc & 7;
            size_t fidx = (size_t)(((bh*44 + gg)*4 + dtv)*2 + hiq)*256 + colr*8 + e;
            if(tt == 0) q  [fidx] = f2bf(v * QSCALE);
            else        kk_[fidx] = f2bf(v);
          }
        } else {
          out[(size_t)row * CH + colc] = v;
        }
      }
    }
  }
}

// ---- flash attention v6: fragment-linear coalesced loads (1KB/instr), 4 waves
// share bh, bijective XCD swizzle, raw s_barrier lockstep, exp2 softmax,
// defer-max (T13), early-V (T14), setprio (T5). ----
__global__ __launch_bounds__(256,3) void k_attn6(
    const u16* __restrict__ Qf, const u16* __restrict__ Kf,
    const u16* __restrict__ Vf, u16* __restrict__ O)
{
  const int bid = blockIdx.x;                 // 0..703
  const int swz = (bid & 7)*88 + (bid >> 3);  // bijective: 704 = 8*88
  const int bh = swz / 11;                    // 8 bh per XCD -> K/V in its L2
  const int qg = swz - bh*11;
  const int w = threadIdx.x >> 6;
  int qt = qg*4 + w;
  const bool wr = (qt < NQT);
  if(!wr) qt = NQT - 1;                       // dup wave: recompute, no store
  const int lane = threadIdx.x & 63;
  const int col = lane & 31;
  const int hi  = lane >> 5;
  const int n0  = qt * 32;
  const size_t lofs = hi*256 + col*8;         // per-lane 16B slot within a 1KB fragment

  s16x8 qf[4];
  {
    const u16* qfb = Qf + (size_t)(bh*44 + qt)*2048 + lofs;
#pragma unroll
    for(int dt=0; dt<4; dt++)
      qf[dt] = *reinterpret_cast<const s16x8*>(qfb + dt*512);
  }
  const u16* kfb = Kf + (size_t)bh*44*2048 + lofs;
  const u16* vfb = Vf + (size_t)bh*22*4096 + lofs;

  f32x16 accO[2];
#pragma unroll
  for(int i=0;i<16;i++){ accO[0][i]=0.f; accO[1][i]=0.f; }
  float m_run = -1e30f, l_run = 0.f;

  for(int kt = 0; kt < NKT64; kt++){
    const int kj0 = kt * 64;
    __builtin_amdgcn_s_barrier();       // lockstep: 4 waves stream same K/V lines
    // ---- QK^T (swapped), coalesced K fragment loads ----
    f32x16 St[2];
    __builtin_amdgcn_s_setprio(1);
#pragma unroll
    for(int s=0;s<2;s++){
#pragma unroll
      for(int i=0;i<16;i++) St[s][i]=0.f;
      const u16* kr = kfb + (size_t)(kt*2+s)*2048;
#pragma unroll
      for(int dt=0;dt<4;dt++){
        s16x8 kf = *reinterpret_cast<const s16x8*>(kr + dt*512);
        St[s] = __builtin_amdgcn_mfma_f32_32x32x16_bf16(kf, qf[dt], St[s], 0,0,0);
      }
    }
    __builtin_amdgcn_s_setprio(0);
    // ---- early V issue (T14): latency hides under softmax ----
    s16x8 vfr[8];
    {
      const u16* vr = vfb + (size_t)kt*4096;
#pragma unroll
      for(int i=0;i<8;i++)
        vfr[i] = *reinterpret_cast<const s16x8*>(vr + i*512);
    }
    // ---- mask (wave-uniform branch) ----
    float p[32];
    if(kj0 + 64 <= SEQ){
#pragma unroll
      for(int i=0;i<32;i++) p[i] = St[i>>4][i&15];
    } else {
#pragma unroll
      for(int s=0;s<2;s++)
#pragma unroll
        for(int r=0;r<16;r++){
          int k = kj0 + s*32 + (r&3) + 8*(r>>2) + 4*hi;
          p[s*16+r] = (k < SEQ) ? St[s][r] : -1e30f;
        }
    }
    // ---- online softmax (base-2), defer-max ----
    float red[16];
#pragma unroll
    for(int i=0;i<16;i++) red[i] = fmaxf(p[i], p[i+16]);
#pragma unroll
    for(int s2=8;s2>=1;s2>>=1)
#pragma unroll
      for(int i=0;i<8;i++) if(i<s2) red[i] = fmaxf(red[i], red[i+s2]);
    float mx = fmaxf(red[0], __shfl_xor(red[0], 32));
    if(!__all(mx <= m_run + 8.f)){   // defer-max (T13)
      float mnew = fmaxf(m_run, mx);
      float alpha = exp2f(m_run - mnew);
      m_run = mnew;
      l_run *= alpha;
#pragma unroll
      for(int i=0;i<16;i++){ accO[0][i]*=alpha; accO[1][i]*=alpha; }
    }
#pragma unroll
    for(int i=0;i<32;i++) p[i] = exp2f(p[i] - m_run);
    float sr[16];
#pragma unroll
    for(int i=0;i<16;i++) sr[i] = p[i] + p[i+16];
#pragma unroll
    for(int s2=8;s2>=1;s2>>=1)
#pragma unroll
      for(int i=0;i<8;i++) if(i<s2) sr[i] += sr[i+s2];
    l_run += sr[0] + __shfl_xor(sr[0], 32);
    // ---- P repack (T12) ----
    union PF { u32 w[4]; s16x8 v; } pf[4];
#pragma unroll
    for(int s=0;s<2;s++){
#pragma unroll
      for(int hh=0; hh<2; hh++){
        const int b0 = s*16 + hh*8;
        u32 w0 = cvt_pk_bf16(p[b0+0], p[b0+1]);
        u32 w1 = cvt_pk_bf16(p[b0+2], p[b0+3]);
        u32 w2 = cvt_pk_bf16(p[b0+4], p[b0+5]);
        u32 w3 = cvt_pk_bf16(p[b0+6], p[b0+7]);
        auto r02 = __builtin_amdgcn_permlane32_swap(w0, w2, false, false);
        auto r13 = __builtin_amdgcn_permlane32_swap(w1, w3, false, false);
        pf[s*2+hh].w[0] = r02[0];
        pf[s*2+hh].w[1] = r13[0];
        pf[s*2+hh].w[2] = r02[1];
        pf[s*2+hh].w[3] = r13[1];
      }
    }
    // ---- PV from prefetched V fragments ----
    __builtin_amdgcn_s_setprio(1);
#pragma unroll
    for(int kh=0; kh<4; kh++)
#pragma unroll
      for(int dt=0; dt<2; dt++)
        accO[dt] = __builtin_amdgcn_mfma_f32_32x32x16_bf16(vfr[kh*2+dt], pf[kh].v, accO[dt], 0,0,0);
    __builtin_amdgcn_s_setprio(0);
  }

  // ---- epilogue ----
  const int n = n0 + col;
  if(wr && n < SEQ){
    float inv = 1.0f / l_run;
    const int b = bh >> 4, h = bh & 15;
    u16* orow = O + ((size_t)(b*SEQ + n))*CH + h*HD;
#pragma unroll
    for(int dt=0; dt<2; dt++)
#pragma unroll
      for(int qd=0; qd<4; qd++){
        u16x4 ov;
#pragma unroll
        for(int j=0;j<4;j++) ov[j] = f2bf(accO[dt][qd*4+j]*inv);
        *reinterpret_cast<u16x4*>(orow + dt*32 + qd*8 + hi*4) = ov;
      }
  }
}

extern "C" void kernel_launch(void* const* d_in, const int* in_sizes, int n_in,
                              void* d_out, int out_size, void* d_ws, size_t ws_size,
                              hipStream_t stream)
{
  const float* tokens = (const float*)d_in[0];
  const float* qkv_w  = (const float*)d_in[1];
  const float* qkv_b  = (const float*)d_in[2];
  const float* proj_w = (const float*)d_in[3];
  const float* proj_b = (const float*)d_in[4];
  float* out = (float*)d_out;

  char* ws = (char*)d_ws;
  u16* Xbf   = (u16*)(ws);              // MPAD*1024*2        = 11,272,192 B
  u16* Wqkv  = (u16*)(ws + 11272192);   // 3072*1024*2        =  6,291,456
  u16* Wproj = (u16*)(ws + 17563648);   // 1024*1024*2        =  2,097,152
  u16* Qfb   = (u16*)(ws + 19660800);   // 64*44*2048*2       = 11,534,336
  u16* Kfb   = (u16*)(ws + 31195136);
  u16* Vfb   = (u16*)(ws + 42729472);
  u16* AttO  = (u16*)(ws + 65798144);   // MPAD*1024*2

  k_cast_tokens<<<dim3((MPAD*CH)/256), 256, 0, stream>>>(tokens, Xbf);
  k_cast<<<dim3((3*CH*CH)/256), 256, 0, stream>>>(qkv_w, Wqkv, 3*CH*CH);
  k_cast<<<dim3((CH*CH)/256),   256, 0, stream>>>(proj_w, Wproj, CH*CH);

  k_gemm128<0,128><<<dim3(1056), 256, 0, stream>>>(Xbf, Wqkv, qkv_b, Qfb, Kfb, Vfb, nullptr);
  k_attn6<<<dim3(704), 256, 0, stream>>>(Qfb, Kfb, Vfb, AttO);
  k_gemm128<1,64><<<dim3(704), 256, 0, stream>>>(AttO, Wproj, proj_b, nullptr, nullptr, nullptr, out);
}